// Round 2
// baseline (255.506 us; speedup 1.0000x reference)
//
#include <hip/hip_runtime.h>

#define ROWS 4096
#define NCOL 8192
#define THREADS 512
#define WAVES (THREADS / 64)            // 8
#define F4PT (NCOL / (THREADS * 4))     // 4 float4 per thread per row
#define RPB 4                           // rows per block (pipelined)
#define GRID (ROWS / RPB)               // 1024 = 4 blocks/CU exactly
#define CAP 128                         // candidate capacity (union of wave-local sets)

typedef float vf4 __attribute__((ext_vector_type(4)));

__global__ __launch_bounds__(THREADS, 8)
void sparsemax_kernel(const float* __restrict__ x, float* __restrict__ out) {
    const int tid  = threadIdx.x;
    const int wave = tid >> 6;
    const int lane = tid & 63;
    const int r0   = blockIdx.x * RPB;

    __shared__ float swv[WAVES];        // fallback only
    __shared__ int   swk[WAVES];        // fallback only
    __shared__ float cand[2][CAP];      // ping-pong by row parity
    __shared__ int   scnt[RPB];         // one counter per row: no reset races

    if (tid < RPB) scnt[tid] = 0;
    __syncthreads();                    // init visible before any gather

    float4 bufA[F4PT], bufB[F4PT];      // register double-buffer (static names: no scratch)
    {
        const float4* __restrict__ xr = (const float4*)(x + (size_t)r0 * NCOL);
#pragma unroll
        for (int j = 0; j < F4PT; ++j) bufA[j] = xr[tid + THREADS * j];
    }

// Process row r0+I held in VC; if PREF, first issue loads of row r0+I+1 into VN
// so they are in flight during this row's gather/solve/store phases.
#define PROCESS_ROW(VC, VN, I, PREF)                                            \
    do {                                                                        \
        if (PREF) {                                                             \
            const float4* __restrict__ xr =                                     \
                (const float4*)(x + (size_t)(r0 + (I) + 1) * NCOL);             \
            _Pragma("unroll")                                                   \
            for (int j = 0; j < F4PT; ++j) VN[j] = xr[tid + THREADS * j];       \
        }                                                                       \
        /* wave-local max (no block barrier needed: wave_max-1 <= tau*) */      \
        float wm = -INFINITY;                                                   \
        _Pragma("unroll")                                                       \
        for (int j = 0; j < F4PT; ++j)                                          \
            wm = fmaxf(wm, fmaxf(fmaxf(VC[j].x, VC[j].y),                       \
                                 fmaxf(VC[j].z, VC[j].w)));                     \
        _Pragma("unroll")                                                       \
        for (int off = 32; off > 0; off >>= 1)                                  \
            wm = fmaxf(wm, __shfl_xor(wm, off, 64));                            \
        const float tw = wm - 1.0f;                                             \
        /* gather candidates (superset of support) into this row's list */      \
        _Pragma("unroll")                                                       \
        for (int j = 0; j < F4PT; ++j) {                                        \
            float4 q = VC[j];                                                   \
            if (q.x > tw) { int p = atomicAdd(&scnt[(I)], 1); if (p < CAP) cand[(I)&1][p] = q.x; } \
            if (q.y > tw) { int p = atomicAdd(&scnt[(I)], 1); if (p < CAP) cand[(I)&1][p] = q.y; } \
            if (q.z > tw) { int p = atomicAdd(&scnt[(I)], 1); if (p < CAP) cand[(I)&1][p] = q.z; } \
            if (q.w > tw) { int p = atomicAdd(&scnt[(I)], 1); if (p < CAP) cand[(I)&1][p] = q.w; } \
        }                                                                       \
        __syncthreads(); /* the ONLY barrier in the fast path */                \
        const int k0 = scnt[(I)];                                               \
        const float c0 = cand[(I)&1][lane];                                     \
        const float c1 = cand[(I)&1][lane + 64];                                \
        float t;                                                                \
        if (k0 <= CAP) {                                                        \
            /* every wave redundantly solves on the tiny list: shuffle-only */  \
            const float q0 = (lane < k0)      ? c0 : -INFINITY;                 \
            const float q1 = (lane + 64 < k0) ? c1 : -INFINITY;                 \
            float mmv = fmaxf(q0, q1);                                          \
            _Pragma("unroll")                                                   \
            for (int off = 32; off > 0; off >>= 1)                              \
                mmv = fmaxf(mmv, __shfl_xor(mmv, off, 64));                     \
            t = mmv - 1.0f;  /* true block max is always in the list */         \
            int prev_k = -1;                                                    \
            for (int it = 0; it < 140; ++it) {                                  \
                float s = 0.0f; int k = 0;                                      \
                if (q0 > t) { s += q0; ++k; }                                   \
                if (q1 > t) { s += q1; ++k; }                                   \
                _Pragma("unroll")                                               \
                for (int off = 32; off > 0; off >>= 1) {                        \
                    s += __shfl_xor(s, off, 64);                                \
                    k += __shfl_xor(k, off, 64);                                \
                }                                                               \
                float tn = (s - 1.0f) / (float)k;                               \
                if (k == prev_k) break;                                         \
                prev_k = k; t = tn;                                             \
            }                                                                   \
        } else {                                                                \
            /* exact fallback: block-wide Michelot over register-resident row */\
            float mmv = fmaxf(c0, c1);  /* all CAP entries valid here */        \
            _Pragma("unroll")                                                   \
            for (int off = 32; off > 0; off >>= 1)                              \
                mmv = fmaxf(mmv, __shfl_xor(mmv, off, 64));                     \
            t = mmv - 1.0f;  /* valid lower bound on tau* */                    \
            int prev_k = -1;                                                    \
            for (int it = 0; it < 300; ++it) {                                  \
                float s = 0.0f; int k = 0;                                      \
                _Pragma("unroll")                                               \
                for (int j = 0; j < F4PT; ++j) {                                \
                    float4 q = VC[j];                                           \
                    if (q.x > t) { s += q.x; ++k; }                             \
                    if (q.y > t) { s += q.y; ++k; }                             \
                    if (q.z > t) { s += q.z; ++k; }                             \
                    if (q.w > t) { s += q.w; ++k; }                             \
                }                                                               \
                _Pragma("unroll")                                               \
                for (int off = 32; off > 0; off >>= 1) {                        \
                    s += __shfl_xor(s, off, 64);                                \
                    k += __shfl_xor(k, off, 64);                                \
                }                                                               \
                if (lane == 0) { swv[wave] = s; swk[wave] = k; }                \
                __syncthreads();                                                \
                float st = 0.0f; int kt = 0;                                    \
                _Pragma("unroll")                                               \
                for (int w = 0; w < WAVES; ++w) { st += swv[w]; kt += swk[w]; } \
                __syncthreads();                                                \
                float tn = (st - 1.0f) / (float)kt;                             \
                if (kt == prev_k) break;                                        \
                prev_k = kt; t = tn;                                            \
            }                                                                   \
        }                                                                       \
        /* epilogue: non-temporal stores (out is never re-read; keep x in L3) */\
        {                                                                       \
            float4* __restrict__ outr = (float4*)(out + (size_t)(r0 + (I)) * NCOL); \
            _Pragma("unroll")                                                   \
            for (int j = 0; j < F4PT; ++j) {                                    \
                float4 q = VC[j];                                               \
                vf4 r;                                                          \
                r.x = fmaxf(q.x - t, 0.0f);                                     \
                r.y = fmaxf(q.y - t, 0.0f);                                     \
                r.z = fmaxf(q.z - t, 0.0f);                                     \
                r.w = fmaxf(q.w - t, 0.0f);                                     \
                __builtin_nontemporal_store(r, (vf4*)&outr[tid + THREADS * j]); \
            }                                                                   \
        }                                                                       \
    } while (0)

    PROCESS_ROW(bufA, bufB, 0, true);
    PROCESS_ROW(bufB, bufA, 1, true);
    PROCESS_ROW(bufA, bufB, 2, true);
    PROCESS_ROW(bufB, bufA, 3, false);

#undef PROCESS_ROW
}

extern "C" void kernel_launch(void* const* d_in, const int* in_sizes, int n_in,
                              void* d_out, int out_size, void* d_ws, size_t ws_size,
                              hipStream_t stream) {
    const float* x = (const float*)d_in[0];
    float* out = (float*)d_out;
    sparsemax_kernel<<<GRID, THREADS, 0, stream>>>(x, out);
}

// Round 3
// 244.094 us; speedup vs baseline: 1.0467x; 1.0467x over previous
//
#include <hip/hip_runtime.h>

#define ROWS 4096
#define NCOL 8192
#define LANES 64
#define F4PL (NCOL / LANES / 4)   // 32 float4 per lane = 128 floats per lane

// One wave per row. No LDS, no barriers, no cross-wave communication.
// All reductions are 64-lane shuffle butterflies.
__global__ __launch_bounds__(LANES, 2)
void sparsemax_kernel(const float* __restrict__ x, float* __restrict__ out) {
    const int row  = blockIdx.x;
    const int lane = threadIdx.x;          // 0..63
    const size_t base = (size_t)row * NCOL;
    const float4* __restrict__ xr  = (const float4*)(x + base);
    float4* __restrict__ outr = (float4*)(out + base);

    // ---- Whole row resident in registers (coalesced float4 loads) ----
    float4 v[F4PL];
#pragma unroll
    for (int j = 0; j < F4PL; ++j) v[j] = xr[lane + LANES * j];

    // ---- Row max (wave butterfly) ----
    float m = -INFINITY;
#pragma unroll
    for (int j = 0; j < F4PL; ++j)
        m = fmaxf(m, fmaxf(fmaxf(v[j].x, v[j].y), fmaxf(v[j].z, v[j].w)));
#pragma unroll
    for (int off = 32; off > 0; off >>= 1)
        m = fmaxf(m, __shfl_xor(m, off, 64));

    const float t0 = m - 1.0f;   // tau* >= max-1: {x > t0} is a superset of the support

    // ---- Per-lane candidate compaction: keep up to 4 values > t0 ----
    float c0 = -INFINITY, c1 = -INFINITY, c2 = -INFINITY, c3 = -INFINITY;
    int cnt = 0;
#define INS(q)                                                         \
    if ((q) > t0) {                                                    \
        if (cnt == 0) c0 = (q);                                        \
        else if (cnt == 1) c1 = (q);                                   \
        else if (cnt == 2) c2 = (q);                                   \
        else if (cnt == 3) c3 = (q);                                   \
        ++cnt;                                                         \
    }
#pragma unroll
    for (int j = 0; j < F4PL; ++j) {
        float4 q = v[j];
        INS(q.x) INS(q.y) INS(q.z) INS(q.w)
    }
#undef INS

    float t = t0;
    if (!__any(cnt > 4)) {
        // ---- Fast path: Michelot on the in-register candidate multiset ----
        // (exact: every threshold ever visited is >= t0, and all values > t0
        //  live in {c0..c3} across the wave)
        int prev_k = -1;
        for (int it = 0; it < 64; ++it) {
            float s = 0.0f; int k = 0;
            if (c0 > t) { s += c0; ++k; }
            if (c1 > t) { s += c1; ++k; }
            if (c2 > t) { s += c2; ++k; }
            if (c3 > t) { s += c3; ++k; }
#pragma unroll
            for (int off = 32; off > 0; off >>= 1) {
                s += __shfl_xor(s, off, 64);
                k += __shfl_xor(k, off, 64);
            }
            if (k == prev_k) break;           // support stable => t == tau* (exact)
            prev_k = k;
            t = (s - 1.0f) / (float)k;
        }
    } else {
        // ---- Exact fallback (rare): full-scan Michelot, still barrier-free ----
        int prev_k = -1;
        for (int it = 0; it < 200; ++it) {
            float s = 0.0f; int k = 0;
#pragma unroll
            for (int j = 0; j < F4PL; ++j) {
                float4 q = v[j];
                if (q.x > t) { s += q.x; ++k; }
                if (q.y > t) { s += q.y; ++k; }
                if (q.z > t) { s += q.z; ++k; }
                if (q.w > t) { s += q.w; ++k; }
            }
#pragma unroll
            for (int off = 32; off > 0; off >>= 1) {
                s += __shfl_xor(s, off, 64);
                k += __shfl_xor(k, off, 64);
            }
            if (k == prev_k) break;
            prev_k = k;
            t = (s - 1.0f) / (float)k;
        }
    }

    // ---- Epilogue: out = max(x - tau, 0) (plain stores; NT hurt in R2) ----
#pragma unroll
    for (int j = 0; j < F4PL; ++j) {
        float4 q = v[j];
        float4 r;
        r.x = fmaxf(q.x - t, 0.0f);
        r.y = fmaxf(q.y - t, 0.0f);
        r.z = fmaxf(q.z - t, 0.0f);
        r.w = fmaxf(q.w - t, 0.0f);
        outr[lane + LANES * j] = r;
    }
}

extern "C" void kernel_launch(void* const* d_in, const int* in_sizes, int n_in,
                              void* d_out, int out_size, void* d_ws, size_t ws_size,
                              hipStream_t stream) {
    const float* x = (const float*)d_in[0];
    float* out = (float*)d_out;
    sparsemax_kernel<<<ROWS, LANES, 0, stream>>>(x, out);
}

// Round 4
// 234.893 us; speedup vs baseline: 1.0878x; 1.0392x over previous
//
#include <hip/hip_runtime.h>

#define ROWS 4096
#define NCOL 8192
#define THREADS 256
#define WAVES (THREADS / 64)        // 4
#define F4PT (NCOL / (THREADS * 4)) // 8 float4 per thread
#define CAP 256                     // candidate list capacity

__global__ __launch_bounds__(THREADS, 8)
void sparsemax_kernel(const float* __restrict__ x, float* __restrict__ out) {
    const int row  = blockIdx.x;
    const int tid  = threadIdx.x;
    const int wave = tid >> 6;
    const int lane = tid & 63;
    const size_t base = (size_t)row * NCOL;
    const float4* __restrict__ xr = (const float4*)(x + base);
    float4* __restrict__ outr     = (float4*)(out + base);

    __shared__ float swm[WAVES];   // wave max
    __shared__ float swe[WAVES];   // wave evicted-max
    __shared__ float cand[CAP];
    __shared__ int   scnt;
    __shared__ float swv[WAVES];   // fallback partial sum
    __shared__ int   swk[WAVES];   // fallback partial count

    if (tid == 0) scnt = 0;

    // ---- Pass 1: the ONLY full-rate scan. Online per-thread top-4 + evicted max.
    float c0 = -INFINITY, c1 = -INFINITY, c2 = -INFINITY, c3 = -INFINITY;
    float e  = -INFINITY;   // max of values evicted from the top-4 (thread's 5th largest)

#define INS(qv) do {                                    \
        float n = (qv), mx;                             \
        mx = fmaxf(c0, n); n = fminf(c0, n); c0 = mx;   \
        mx = fmaxf(c1, n); n = fminf(c1, n); c1 = mx;   \
        mx = fmaxf(c2, n); n = fminf(c2, n); c2 = mx;   \
        mx = fmaxf(c3, n); n = fminf(c3, n); c3 = mx;   \
        e = fmaxf(e, n);                                \
    } while (0)

#pragma unroll
    for (int j = 0; j < F4PT; ++j) {
        float4 q = xr[tid + THREADS * j];
        INS(q.x); INS(q.y); INS(q.z); INS(q.w);
    }
#undef INS

    // ---- Block max (and block evicted-max), one barrier ----
    float m = c0, ew = e;
#pragma unroll
    for (int off = 32; off > 0; off >>= 1) {
        m  = fmaxf(m,  __shfl_xor(m,  off, 64));
        ew = fmaxf(ew, __shfl_xor(ew, off, 64));
    }
    if (lane == 0) { swm[wave] = m; swe[wave] = ew; }
    __syncthreads();                                   // (1) also covers scnt init
    float bm = swm[0], be = swe[0];
#pragma unroll
    for (int w = 1; w < WAVES; ++w) { bm = fmaxf(bm, swm[w]); be = fmaxf(be, swe[w]); }
    const float t0 = bm - 1.0f;   // tau* >= max-1

    // ---- Push candidates (> t0) from the per-thread top-4 (expected ~21 total) ----
    if (c0 > t0) { int p = atomicAdd(&scnt, 1); if (p < CAP) cand[p] = c0; }
    if (c1 > t0) { int p = atomicAdd(&scnt, 1); if (p < CAP) cand[p] = c1; }
    if (c2 > t0) { int p = atomicAdd(&scnt, 1); if (p < CAP) cand[p] = c2; }
    if (c3 > t0) { int p = atomicAdd(&scnt, 1); if (p < CAP) cand[p] = c3; }
    __syncthreads();                                   // (2)

    const int k0 = scnt;
    float t = t0;
    bool need_full = (k0 > CAP);

    if (!need_full) {
        // Every wave solves redundantly on the tiny list: shuffle-only, no barriers.
        // Deterministic identical result in all waves (same list, same ops).
        const float q0 = (lane       < k0) ? cand[lane      ] : -INFINITY;
        const float q1 = (lane + 64  < k0) ? cand[lane + 64 ] : -INFINITY;
        const float q2 = (lane + 128 < k0) ? cand[lane + 128] : -INFINITY;
        const float q3 = (lane + 192 < k0) ? cand[lane + 192] : -INFINITY;
        int prev_k = -1;
        for (int it = 0; it < 64; ++it) {
            float s = 0.0f; int k = 0;
            if (q0 > t) { s += q0; ++k; }
            if (q1 > t) { s += q1; ++k; }
            if (q2 > t) { s += q2; ++k; }
            if (q3 > t) { s += q3; ++k; }
#pragma unroll
            for (int off = 32; off > 0; off >>= 1) {
                s += __shfl_xor(s, off, 64);
                k += __shfl_xor(k, off, 64);
            }
            if (k == prev_k) break;        // support stable => t is the fixed point
            prev_k = k;
            t = (s - 1.0f) / (float)k;
        }
        // Validity: if the largest value ANY thread evicted exceeds tau, the
        // candidate union may have missed support elements -> exact fallback.
        need_full = (be > t);
    }

    if (need_full) {
        // ---- Exact fallback (cold: requires >=5 support values in one thread) ----
        // Block-wide Michelot re-scanning the row from cache. t is a valid
        // lower bound on tau* here (t0, or the candidate-set fixed point <= tau*).
        int prev_k = -1;
        for (int it = 0; it < 200; ++it) {
            float s = 0.0f; int k = 0;
#pragma unroll
            for (int j = 0; j < F4PT; ++j) {
                float4 q = xr[tid + THREADS * j];
                if (q.x > t) { s += q.x; ++k; }
                if (q.y > t) { s += q.y; ++k; }
                if (q.z > t) { s += q.z; ++k; }
                if (q.w > t) { s += q.w; ++k; }
            }
#pragma unroll
            for (int off = 32; off > 0; off >>= 1) {
                s += __shfl_xor(s, off, 64);
                k += __shfl_xor(k, off, 64);
            }
            if (lane == 0) { swv[wave] = s; swk[wave] = k; }
            __syncthreads();
            float st = 0.0f; int kt = 0;
#pragma unroll
            for (int w = 0; w < WAVES; ++w) { st += swv[w]; kt += swk[w]; }
            __syncthreads();
            if (kt == prev_k) break;       // uniform across block
            prev_k = kt;
            t = (st - 1.0f) / (float)kt;
        }
    }

    // ---- Pass 2: re-read row (L2-hot), apply threshold, store ----
#pragma unroll
    for (int j = 0; j < F4PT; ++j) {
        float4 q = xr[tid + THREADS * j];
        float4 r;
        r.x = fmaxf(q.x - t, 0.0f);
        r.y = fmaxf(q.y - t, 0.0f);
        r.z = fmaxf(q.z - t, 0.0f);
        r.w = fmaxf(q.w - t, 0.0f);
        outr[tid + THREADS * j] = r;
    }
}

extern "C" void kernel_launch(void* const* d_in, const int* in_sizes, int n_in,
                              void* d_out, int out_size, void* d_ws, size_t ws_size,
                              hipStream_t stream) {
    const float* x = (const float*)d_in[0];
    float* out = (float*)d_out;
    sparsemax_kernel<<<ROWS, THREADS, 0, stream>>>(x, out);
}

// Round 5
// 231.179 us; speedup vs baseline: 1.1052x; 1.0161x over previous
//
#include <hip/hip_runtime.h>

#define ROWS 4096
#define NCOL 8192
#define THREADS 256
#define WAVES (THREADS / 64)        // 4
#define F4PT (NCOL / (THREADS * 4)) // 8 float4 per thread
#define LDSF4 6                     // float4/thread staged in LDS (j=0..5); j=6,7 stay in regs
#define CAP 256                     // candidate list capacity

__global__ __launch_bounds__(THREADS, 6)
void sparsemax_kernel(const float* __restrict__ x, float* __restrict__ out) {
    const int row  = blockIdx.x;
    const int tid  = threadIdx.x;
    const int wave = tid >> 6;
    const int lane = tid & 63;
    const size_t base = (size_t)row * NCOL;
    const float4* __restrict__ xr = (const float4*)(x + base);
    float4* __restrict__ outr     = (float4*)(out + base);

    __shared__ float4 srow[THREADS * LDSF4];  // 24 KiB: thread-private row stash
    __shared__ float swm[WAVES];   // wave max
    __shared__ float swe[WAVES];   // wave evicted-max
    __shared__ float cand[CAP];
    __shared__ int   scnt;
    __shared__ float swv[WAVES];   // fallback partial sum
    __shared__ int   swk[WAVES];   // fallback partial count

    if (tid == 0) scnt = 0;

    // ---- Pass 1: the ONLY global scan. Online top-4 + evicted max; stash row in LDS.
    float c0 = -INFINITY, c1 = -INFINITY, c2 = -INFINITY, c3 = -INFINITY;
    float e  = -INFINITY;   // max of values evicted from the top-4 (thread's 5th largest)
    float4 v6, v7;          // last two float4 kept in registers (LDS budget: 6 blocks/CU)

#define INS(qv) do {                                    \
        float n = (qv), mx;                             \
        mx = fmaxf(c0, n); n = fminf(c0, n); c0 = mx;   \
        mx = fmaxf(c1, n); n = fminf(c1, n); c1 = mx;   \
        mx = fmaxf(c2, n); n = fminf(c2, n); c2 = mx;   \
        mx = fmaxf(c3, n); n = fminf(c3, n); c3 = mx;   \
        e = fmaxf(e, n);                                \
    } while (0)

#pragma unroll
    for (int j = 0; j < LDSF4; ++j) {
        float4 q = xr[tid + THREADS * j];
        srow[tid + THREADS * j] = q;          // each thread reads back ONLY its own slots
        INS(q.x); INS(q.y); INS(q.z); INS(q.w);
    }
    v6 = xr[tid + THREADS * 6];
    INS(v6.x); INS(v6.y); INS(v6.z); INS(v6.w);
    v7 = xr[tid + THREADS * 7];
    INS(v7.x); INS(v7.y); INS(v7.z); INS(v7.w);
#undef INS

    // ---- Block max + block evicted-max ----
    float m = c0, ew = e;
#pragma unroll
    for (int off = 32; off > 0; off >>= 1) {
        m  = fmaxf(m,  __shfl_xor(m,  off, 64));
        ew = fmaxf(ew, __shfl_xor(ew, off, 64));
    }
    if (lane == 0) { swm[wave] = m; swe[wave] = ew; }
    __syncthreads();                                   // (1) also covers scnt init
    float bm = swm[0], be = swe[0];
#pragma unroll
    for (int w = 1; w < WAVES; ++w) { bm = fmaxf(bm, swm[w]); be = fmaxf(be, swe[w]); }
    const float t0 = bm - 1.0f;   // tau* >= max-1

    // ---- Push candidates (> t0) from per-thread top-4 (expected ~21 total) ----
    if (c0 > t0) { int p = atomicAdd(&scnt, 1); if (p < CAP) cand[p] = c0; }
    if (c1 > t0) { int p = atomicAdd(&scnt, 1); if (p < CAP) cand[p] = c1; }
    if (c2 > t0) { int p = atomicAdd(&scnt, 1); if (p < CAP) cand[p] = c2; }
    if (c3 > t0) { int p = atomicAdd(&scnt, 1); if (p < CAP) cand[p] = c3; }
    __syncthreads();                                   // (2) last barrier in fast path

    const int k0 = scnt;
    float t = t0;
    bool need_full = (k0 > CAP);

    if (!need_full) {
        // Wave-redundant Michelot on the tiny list: shuffle-only, no barriers,
        // deterministic identical result in every wave.
        const float q0 = (lane       < k0) ? cand[lane      ] : -INFINITY;
        const float q1 = (lane + 64  < k0) ? cand[lane + 64 ] : -INFINITY;
        const float q2 = (lane + 128 < k0) ? cand[lane + 128] : -INFINITY;
        const float q3 = (lane + 192 < k0) ? cand[lane + 192] : -INFINITY;
        int prev_k = -1;
        for (int it = 0; it < 64; ++it) {
            float s = 0.0f; int k = 0;
            if (q0 > t) { s += q0; ++k; }
            if (q1 > t) { s += q1; ++k; }
            if (q2 > t) { s += q2; ++k; }
            if (q3 > t) { s += q3; ++k; }
#pragma unroll
            for (int off = 32; off > 0; off >>= 1) {
                s += __shfl_xor(s, off, 64);
                k += __shfl_xor(k, off, 64);
            }
            if (k == prev_k) break;        // support stable => t is the fixed point
            prev_k = k;
            t = (s - 1.0f) / (float)k;
        }
        // Validity: if any thread's evicted max exceeds tau, the candidate union
        // may have missed support elements -> exact fallback.
        need_full = (be > t);
    }

    if (need_full) {
        // ---- Exact fallback (cold: needs >=5 support values in one thread) ----
        // Block-wide Michelot; row comes from LDS + the two register float4s.
        int prev_k = -1;
        for (int it = 0; it < 200; ++it) {
            float s = 0.0f; int k = 0;
#pragma unroll
            for (int j = 0; j < LDSF4; ++j) {
                float4 q = srow[tid + THREADS * j];
                if (q.x > t) { s += q.x; ++k; }
                if (q.y > t) { s += q.y; ++k; }
                if (q.z > t) { s += q.z; ++k; }
                if (q.w > t) { s += q.w; ++k; }
            }
            if (v6.x > t) { s += v6.x; ++k; }
            if (v6.y > t) { s += v6.y; ++k; }
            if (v6.z > t) { s += v6.z; ++k; }
            if (v6.w > t) { s += v6.w; ++k; }
            if (v7.x > t) { s += v7.x; ++k; }
            if (v7.y > t) { s += v7.y; ++k; }
            if (v7.z > t) { s += v7.z; ++k; }
            if (v7.w > t) { s += v7.w; ++k; }
#pragma unroll
            for (int off = 32; off > 0; off >>= 1) {
                s += __shfl_xor(s, off, 64);
                k += __shfl_xor(k, off, 64);
            }
            if (lane == 0) { swv[wave] = s; swk[wave] = k; }
            __syncthreads();
            float st = 0.0f; int kt = 0;
#pragma unroll
            for (int w = 0; w < WAVES; ++w) { st += swv[w]; kt += swk[w]; }
            __syncthreads();
            if (kt == prev_k) break;       // uniform decision across block
            prev_k = kt;
            t = (st - 1.0f) / (float)kt;
        }
    }

    // ---- Epilogue: row from LDS/regs (NO global re-read), plain stores ----
#pragma unroll
    for (int j = 0; j < LDSF4; ++j) {
        float4 q = srow[tid + THREADS * j];   // own slots: no barrier needed
        float4 r;
        r.x = fmaxf(q.x - t, 0.0f);
        r.y = fmaxf(q.y - t, 0.0f);
        r.z = fmaxf(q.z - t, 0.0f);
        r.w = fmaxf(q.w - t, 0.0f);
        outr[tid + THREADS * j] = r;
    }
    {
        float4 r;
        r.x = fmaxf(v6.x - t, 0.0f);
        r.y = fmaxf(v6.y - t, 0.0f);
        r.z = fmaxf(v6.z - t, 0.0f);
        r.w = fmaxf(v6.w - t, 0.0f);
        outr[tid + THREADS * 6] = r;
        r.x = fmaxf(v7.x - t, 0.0f);
        r.y = fmaxf(v7.y - t, 0.0f);
        r.z = fmaxf(v7.z - t, 0.0f);
        r.w = fmaxf(v7.w - t, 0.0f);
        outr[tid + THREADS * 7] = r;
    }
}

extern "C" void kernel_launch(void* const* d_in, const int* in_sizes, int n_in,
                              void* d_out, int out_size, void* d_ws, size_t ws_size,
                              hipStream_t stream) {
    const float* x = (const float*)d_in[0];
    float* out = (float*)d_out;
    sparsemax_kernel<<<ROWS, THREADS, 0, stream>>>(x, out);
}